// Round 12
// baseline (321.279 us; speedup 1.0000x reference)
//
#include <hip/hip_runtime.h>
#include <hip/hip_fp16.h>

// SGC forward, GEMM-commuted, fp16 gather tables.
//   dinv[i] = rsqrt(indeg[i]+1)
//   y1  = fp16( dinv .* (x @ W1^T) )                 (gemm1: fp32 in, fp16 out)
//   h1s = fp16( dinv .* relu( dinv[d]*(sum y1[s] + y1[d]) + b1 ) )  (gather1)
//   y2  = fp16( h1s @ W2^T )                         (gemm2: fp16 in, fp16 out)
//   out = relu( dinv[d]*(sum y2[s] + y2[d]) + b2 ) @ W3^T + b3      (gather2 + W3)
// Empirical laws (rounds 6-11):
//  - gather dur invariant to fetch volume => latency/stall-bound. This round:
//    16-deep unroll (16 idx in flight, then 16 row loads) halves stalls/edge.
//  - NT stores on producer->consumer scratch (r11): -45us regression. REVERTED.
//  - XCD slicing, fused weight-tile epilogues in gathers: regress. Keep out.
//  - streaming readlane GEMMs ~12us: keep.

#define F 64
#define C 16
#define SCAN_B 1024

__device__ __forceinline__ float rl(float v, int l) {
    return __uint_as_float(__builtin_amdgcn_readlane(__float_as_uint(v), l));
}

__device__ __forceinline__ float4 unpack_h4(unsigned long long raw) {
    __half2 lo = __builtin_bit_cast(__half2, (unsigned int)(raw & 0xffffffffull));
    __half2 hi = __builtin_bit_cast(__half2, (unsigned int)(raw >> 32));
    float2 f0 = __half22float2(lo);
    float2 f1 = __half22float2(hi);
    return make_float4(f0.x, f0.y, f1.x, f1.y);
}

// ---- histogram + per-edge rank (one atomic pass) ----
__global__ void degrank_kernel(const int* __restrict__ dst, int* __restrict__ deg,
                               int* __restrict__ rank, int E) {
    int i = (blockIdx.x * blockDim.x + threadIdx.x) * 4;
    if (i + 4 <= E) {
        int4 d = *(const int4*)(dst + i);
        int4 r;
        r.x = atomicAdd(&deg[d.x], 1);
        r.y = atomicAdd(&deg[d.y], 1);
        r.z = atomicAdd(&deg[d.z], 1);
        r.w = atomicAdd(&deg[d.w], 1);
        *(int4*)(rank + i) = r;
    } else {
        for (int k = i; k < E; ++k) rank[k] = atomicAdd(&deg[dst[k]], 1);
    }
}

// ---- exclusive scan of deg -> rowptr ----
__global__ __launch_bounds__(256) void scan1_kernel(const int* __restrict__ deg,
                                                    int* __restrict__ part,
                                                    int* __restrict__ bsum, int n) {
    __shared__ int ts[256];
    int b = blockIdx.x, t = threadIdx.x;
    int base = b * SCAN_B + t * 4;
    int v[4], sum = 0;
#pragma unroll
    for (int k = 0; k < 4; ++k) { int i = base + k; v[k] = (i < n) ? deg[i] : 0; sum += v[k]; }
    ts[t] = sum;
    __syncthreads();
    for (int off = 1; off < 256; off <<= 1) {
        int add = (t >= off) ? ts[t - off] : 0;
        __syncthreads();
        ts[t] += add;
        __syncthreads();
    }
    int run = ts[t] - sum;
#pragma unroll
    for (int k = 0; k < 4; ++k) { int i = base + k; if (i < n) part[i] = run; run += v[k]; }
    if (t == 255) bsum[b] = ts[255];
}

__global__ __launch_bounds__(256) void scan2_kernel(int* __restrict__ bsum, int nb) {
    __shared__ int ts[256];
    int t = threadIdx.x;
    int v = (t < nb) ? bsum[t] : 0;
    ts[t] = v;
    __syncthreads();
    for (int off = 1; off < 256; off <<= 1) {
        int add = (t >= off) ? ts[t - off] : 0;
        __syncthreads();
        ts[t] += add;
        __syncthreads();
    }
    if (t < nb) bsum[t] = ts[t] - v;
}

__global__ void scan3_kernel(const int* __restrict__ part, const int* __restrict__ bsum,
                             const int* __restrict__ deg, int* __restrict__ rowptr,
                             float* __restrict__ dinv, int n, int E) {
    int i = blockIdx.x * blockDim.x + threadIdx.x;
    if (i < n) {
        rowptr[i] = part[i] + bsum[i / SCAN_B];
        dinv[i] = rsqrtf((float)deg[i] + 1.0f);
    }
    if (i == 0) rowptr[n] = E;
}

// ---- atomic-free bucket fill (plain stores; L2 write-back is the fast path) ----
__global__ void fill_kernel(const int* __restrict__ src, const int* __restrict__ dst,
                            const int* __restrict__ rank, const int* __restrict__ rowptr,
                            int* __restrict__ csr_src, int E) {
    int i = (blockIdx.x * blockDim.x + threadIdx.x) * 4;
    if (i + 4 <= E) {
        int4 s = *(const int4*)(src + i);
        int4 d = *(const int4*)(dst + i);
        int4 r = *(const int4*)(rank + i);
        csr_src[rowptr[d.x] + r.x] = s.x;
        csr_src[rowptr[d.y] + r.y] = s.y;
        csr_src[rowptr[d.z] + r.z] = s.z;
        csr_src[rowptr[d.w] + r.w] = s.w;
    } else {
        for (int k = i; k < E; ++k) csr_src[rowptr[dst[k]] + rank[k]] = src[k];
    }
}

// ---- gemm1: y1[i][j] = fp16( scale[i] * (x[i] . W1[j]) ), fp32 input ----
__global__ __launch_bounds__(256) void gemm1_kernel(
    const float4* __restrict__ in4, const float* __restrict__ W,
    const float* __restrict__ scale, __half* __restrict__ yout, int n) {
    int tid = threadIdx.x;
    int lane = tid & 63;
    int m = lane & 15;
    float4 w[16];
#pragma unroll
    for (int t = 0; t < 16; ++t) w[t] = *(const float4*)(W + (size_t)lane * F + 4 * t);
    int gw = blockIdx.x * 4 + (tid >> 6);
    int nw = gridDim.x * 4;
    int node = gw;
    if (node >= n) return;
    float4 v = in4[(size_t)node * 16 + m];
    while (true) {
        int nxt = node + nw;
        float4 vn;
        if (nxt < n) vn = in4[(size_t)nxt * 16 + m];   // prefetch next row
        float acc = 0.0f;
#pragma unroll
        for (int t = 0; t < 16; ++t) {
            acc = fmaf(rl(v.x, t), w[t].x, acc);
            acc = fmaf(rl(v.y, t), w[t].y, acc);
            acc = fmaf(rl(v.z, t), w[t].z, acc);
            acc = fmaf(rl(v.w, t), w[t].w, acc);
        }
        acc *= scale[node];
        yout[(size_t)node * F + lane] = __float2half(acc);
        if (nxt >= n) break;
        v = vn;
        node = nxt;
    }
}

// ---- gemm2: y2[i][j] = fp16( (h1s[i] . W2[j]) ), fp16 input ----
__global__ __launch_bounds__(256) void gemm2_kernel(
    const unsigned long long* __restrict__ in8, const float* __restrict__ W,
    __half* __restrict__ yout, int n) {
    int tid = threadIdx.x;
    int lane = tid & 63;
    int m = lane & 15;
    float4 w[16];
#pragma unroll
    for (int t = 0; t < 16; ++t) w[t] = *(const float4*)(W + (size_t)lane * F + 4 * t);
    int gw = blockIdx.x * 4 + (tid >> 6);
    int nw = gridDim.x * 4;
    int node = gw;
    if (node >= n) return;
    float4 v = unpack_h4(in8[(size_t)node * 16 + m]);
    while (true) {
        int nxt = node + nw;
        float4 vn;
        if (nxt < n) vn = unpack_h4(in8[(size_t)nxt * 16 + m]);   // prefetch
        float acc = 0.0f;
#pragma unroll
        for (int t = 0; t < 16; ++t) {
            acc = fmaf(rl(v.x, t), w[t].x, acc);
            acc = fmaf(rl(v.y, t), w[t].y, acc);
            acc = fmaf(rl(v.z, t), w[t].z, acc);
            acc = fmaf(rl(v.w, t), w[t].w, acc);
        }
        yout[(size_t)node * F + lane] = __float2half(acc);
        if (nxt >= n) break;
        v = vn;
        node = nxt;
    }
}

// ---- gather1: quarter-wave per node; 16-deep unrolled fp16 gather -> h1s (fp16) ----
__global__ __launch_bounds__(256) void gather1_kernel(
    const unsigned long long* __restrict__ y, const int* __restrict__ rowptr,
    const int* __restrict__ csr_src, const float* __restrict__ dinv,
    const float* __restrict__ b1, __half* __restrict__ h1s, int n) {
    int tid = threadIdx.x;
    int m = tid & 15;
    float4 bias = *(const float4*)(b1 + 4 * m);
    int qid = (blockIdx.x * 256 + tid) >> 4;   // global quarter id
    int nq = (gridDim.x * 256) >> 4;
    for (int node = qid; node < n; node += nq) {
        int beg = rowptr[node], end = rowptr[node + 1];
        float4 acc[4] = {{0,0,0,0},{0,0,0,0},{0,0,0,0},{0,0,0,0}};
        int p = beg;
        for (; p + 16 <= end; p += 16) {       // 16 idx in flight, then 16 rows
            int sidx[16];
#pragma unroll
            for (int k = 0; k < 16; ++k) sidx[k] = csr_src[p + k];
            unsigned long long raw[16];
#pragma unroll
            for (int k = 0; k < 16; ++k) raw[k] = y[(size_t)sidx[k] * 16 + m];
#pragma unroll
            for (int k = 0; k < 16; ++k) {
                float4 v = unpack_h4(raw[k]);
                acc[k & 3].x += v.x; acc[k & 3].y += v.y;
                acc[k & 3].z += v.z; acc[k & 3].w += v.w;
            }
        }
        if (p + 8 <= end) {
            int sidx[8];
#pragma unroll
            for (int k = 0; k < 8; ++k) sidx[k] = csr_src[p + k];
            unsigned long long raw[8];
#pragma unroll
            for (int k = 0; k < 8; ++k) raw[k] = y[(size_t)sidx[k] * 16 + m];
#pragma unroll
            for (int k = 0; k < 8; ++k) {
                float4 v = unpack_h4(raw[k]);
                acc[k & 3].x += v.x; acc[k & 3].y += v.y;
                acc[k & 3].z += v.z; acc[k & 3].w += v.w;
            }
            p += 8;
        }
        for (; p < end; ++p) {
            float4 v = unpack_h4(y[(size_t)csr_src[p] * 16 + m]);
            acc[0].x += v.x; acc[0].y += v.y; acc[0].z += v.z; acc[0].w += v.w;
        }
        float4 a;
        a.x = acc[0].x + acc[1].x + acc[2].x + acc[3].x;
        a.y = acc[0].y + acc[1].y + acc[2].y + acc[3].y;
        a.z = acc[0].z + acc[1].z + acc[2].z + acc[3].z;
        a.w = acc[0].w + acc[1].w + acc[2].w + acc[3].w;
        float dd = dinv[node];
        float4 self = unpack_h4(y[(size_t)node * 16 + m]);
        float4 r;
        r.x = dd * fmaxf(fmaf(dd, a.x + self.x, bias.x), 0.0f);
        r.y = dd * fmaxf(fmaf(dd, a.y + self.y, bias.y), 0.0f);
        r.z = dd * fmaxf(fmaf(dd, a.z + self.z, bias.z), 0.0f);
        r.w = dd * fmaxf(fmaf(dd, a.w + self.w, bias.w), 0.0f);
        __half2 lo = __float22half2_rn(make_float2(r.x, r.y));
        __half2 hi = __float22half2_rn(make_float2(r.z, r.w));
        float2 packed;
        packed.x = __builtin_bit_cast(float, lo);
        packed.y = __builtin_bit_cast(float, hi);
        *(float2*)(h1s + (size_t)node * F + 4 * m) = packed;
    }
}

// ---- gather2: quarter-wave, 16-deep unroll + b2/relu + W3 (shfl) -> out ----
__global__ __launch_bounds__(256) void gather2_kernel(
    const unsigned long long* __restrict__ y, const int* __restrict__ rowptr,
    const int* __restrict__ csr_src, const float* __restrict__ dinv,
    const float* __restrict__ b2, const float* __restrict__ W3,
    const float* __restrict__ b3, float* __restrict__ out, int n) {
    int tid = threadIdx.x;
    int lane = tid & 63;
    int m = lane & 15;
    int qbase = lane & 48;
    float4 bias = *(const float4*)(b2 + 4 * m);
    float b3r = b3[m];
    int qid = (blockIdx.x * 256 + tid) >> 4;
    int nq = (gridDim.x * 256) >> 4;
    for (int node = qid; node < n; node += nq) {
        int beg = rowptr[node], end = rowptr[node + 1];
        float4 acc[4] = {{0,0,0,0},{0,0,0,0},{0,0,0,0},{0,0,0,0}};
        int p = beg;
        for (; p + 16 <= end; p += 16) {
            int sidx[16];
#pragma unroll
            for (int k = 0; k < 16; ++k) sidx[k] = csr_src[p + k];
            unsigned long long raw[16];
#pragma unroll
            for (int k = 0; k < 16; ++k) raw[k] = y[(size_t)sidx[k] * 16 + m];
#pragma unroll
            for (int k = 0; k < 16; ++k) {
                float4 v = unpack_h4(raw[k]);
                acc[k & 3].x += v.x; acc[k & 3].y += v.y;
                acc[k & 3].z += v.z; acc[k & 3].w += v.w;
            }
        }
        if (p + 8 <= end) {
            int sidx[8];
#pragma unroll
            for (int k = 0; k < 8; ++k) sidx[k] = csr_src[p + k];
            unsigned long long raw[8];
#pragma unroll
            for (int k = 0; k < 8; ++k) raw[k] = y[(size_t)sidx[k] * 16 + m];
#pragma unroll
            for (int k = 0; k < 8; ++k) {
                float4 v = unpack_h4(raw[k]);
                acc[k & 3].x += v.x; acc[k & 3].y += v.y;
                acc[k & 3].z += v.z; acc[k & 3].w += v.w;
            }
            p += 8;
        }
        for (; p < end; ++p) {
            float4 v = unpack_h4(y[(size_t)csr_src[p] * 16 + m]);
            acc[0].x += v.x; acc[0].y += v.y; acc[0].z += v.z; acc[0].w += v.w;
        }
        float4 a;
        a.x = acc[0].x + acc[1].x + acc[2].x + acc[3].x;
        a.y = acc[0].y + acc[1].y + acc[2].y + acc[3].y;
        a.z = acc[0].z + acc[1].z + acc[2].z + acc[3].z;
        a.w = acc[0].w + acc[1].w + acc[2].w + acc[3].w;
        float dd = dinv[node];
        float4 self = unpack_h4(y[(size_t)node * 16 + m]);
        float4 h;   // lane m of quarter: h2 features [4m..4m+3]
        h.x = fmaxf(fmaf(dd, a.x + self.x, bias.x), 0.0f);
        h.y = fmaxf(fmaf(dd, a.y + self.y, bias.y), 0.0f);
        h.z = fmaxf(fmaf(dd, a.z + self.z, bias.z), 0.0f);
        h.w = fmaxf(fmaf(dd, a.w + self.w, bias.w), 0.0f);
        // out[node][m] = b3[m] + sum_t dot(h2[4t..4t+3], W3[m][4t..4t+3])
        float acc3 = 0.0f;
#pragma unroll
        for (int t = 0; t < 16; ++t) {
            float4 wv = *(const float4*)(W3 + (size_t)m * F + 4 * t);   // L1-hot
            float hx = __shfl(h.x, qbase + t);
            float hy = __shfl(h.y, qbase + t);
            float hz = __shfl(h.z, qbase + t);
            float hw = __shfl(h.w, qbase + t);
            acc3 = fmaf(hx, wv.x, fmaf(hy, wv.y, fmaf(hz, wv.z, fmaf(hw, wv.w, acc3))));
        }
        out[(size_t)node * C + m] = acc3 + b3r;
    }
}

extern "C" void kernel_launch(void* const* d_in, const int* in_sizes, int n_in,
                              void* d_out, int out_size, void* d_ws, size_t ws_size,
                              hipStream_t stream) {
    const float* x  = (const float*)d_in[0];
    const int* edge = (const int*)d_in[1];
    const float* W1 = (const float*)d_in[2];
    const float* b1 = (const float*)d_in[3];
    const float* W2 = (const float*)d_in[4];
    const float* b2 = (const float*)d_in[5];
    const float* W3 = (const float*)d_in[6];
    const float* b3 = (const float*)d_in[7];
    float* out = (float*)d_out;

    int n = in_sizes[0] / F;        // 100000
    int E = in_sizes[1] / 2;        // 1600000
    const int* src = edge;
    const int* dst = edge + E;

    int nb = (n + SCAN_B - 1) / SCAN_B;

    char* ws = (char*)d_ws;
    size_t o = 0;
    auto alloc = [&](size_t bytes) { char* p = ws + o; o += (bytes + 255) & ~(size_t)255; return p; };
    int*    deg     = (int*)   alloc((size_t)n * 4);
    int*    rank    = (int*)   alloc((size_t)E * 4);
    int*    part    = (int*)   alloc((size_t)n * 4);
    int*    bsum    = (int*)   alloc(256 * 4);
    int*    rowptr  = (int*)   alloc((size_t)(n + 1) * 4);
    int*    csr_src = (int*)   alloc((size_t)E * 4);
    float*  dinv    = (float*) alloc((size_t)n * 4);
    __half* y1      = (__half*)alloc((size_t)n * F * 2);   // reused as y2
    __half* h1s     = (__half*)alloc((size_t)n * F * 2);
    __half* y2      = y1;                                   // y1 dead after gather1

    hipMemsetAsync(deg, 0, (size_t)n * 4, stream);
    degrank_kernel<<<(E / 4 + 255) / 256, 256, 0, stream>>>(dst, deg, rank, E);

    scan1_kernel<<<nb, 256, 0, stream>>>(deg, part, bsum, n);
    scan2_kernel<<<1, 256, 0, stream>>>(bsum, nb);
    scan3_kernel<<<(n + 255) / 256, 256, 0, stream>>>(part, bsum, deg, rowptr, dinv, n, E);

    // y1 = fp16( dinv .* (x @ W1^T) )
    gemm1_kernel<<<2048, 256, 0, stream>>>((const float4*)x, W1, dinv, y1, n);

    fill_kernel<<<(E / 4 + 255) / 256, 256, 0, stream>>>(src, dst, rank, rowptr, csr_src, E);

    gather1_kernel<<<2048, 256, 0, stream>>>(
        (const unsigned long long*)y1, rowptr, csr_src, dinv, b1, h1s, n);

    // y2 = fp16( h1s @ W2^T )
    gemm2_kernel<<<2048, 256, 0, stream>>>(
        (const unsigned long long*)h1s, W2, y2, n);

    gather2_kernel<<<2048, 256, 0, stream>>>(
        (const unsigned long long*)y2, rowptr, csr_src, dinv, b2, W3, b3, out, n);
}

// Round 14
// 287.482 us; speedup vs baseline: 1.1176x; 1.1176x over previous
//
#include <hip/hip_runtime.h>
#include <hip/hip_fp16.h>

// SGC forward, GEMM-commuted, fp16 gather tables.
//   dinv[i] = rsqrt(indeg[i]+1)
//   y1  = fp16( dinv .* (x @ W1^T) )                 (gemm1: fp32 in, fp16 out)
//   h1s = fp16( dinv .* relu( dinv[d]*(sum y1[s] + y1[d]) + b1 ) )  (gather1)
//   y2  = fp16( h1s @ W2^T )                         (gemm2: fp16 in, fp16 out)
//   out = relu( dinv[d]*(sum y2[s] + y2[d]) + b2 ) @ W3^T + b3      (gather2 + W3)
// Empirical laws (rounds 6-12):
//  - gather dur invariant to fetch volume => latency-bound on row round-trips.
//  - 8-deep interleaved body = best (74us); 16-deep batched = 87us. REVERTED.
//  - NT stores on producer->consumer scratch: -45us. REVERTED (plain stores).
//  - XCD slicing, fused weight epilogues in gathers: regress. Keep out.
//  - This round: index-prefetch pipeline in the 8-deep body (next 8 csr
//    indices issued while current 8 row loads are in flight).

#define F 64
#define C 16
#define SCAN_B 1024

__device__ __forceinline__ float rl(float v, int l) {
    return __uint_as_float(__builtin_amdgcn_readlane(__float_as_uint(v), l));
}

__device__ __forceinline__ float4 unpack_h4(unsigned long long raw) {
    __half2 lo = __builtin_bit_cast(__half2, (unsigned int)(raw & 0xffffffffull));
    __half2 hi = __builtin_bit_cast(__half2, (unsigned int)(raw >> 32));
    float2 f0 = __half22float2(lo);
    float2 f1 = __half22float2(hi);
    return make_float4(f0.x, f0.y, f1.x, f1.y);
}

// ---- histogram + per-edge rank (one atomic pass) ----
__global__ void degrank_kernel(const int* __restrict__ dst, int* __restrict__ deg,
                               int* __restrict__ rank, int E) {
    int i = (blockIdx.x * blockDim.x + threadIdx.x) * 4;
    if (i + 4 <= E) {
        int4 d = *(const int4*)(dst + i);
        int4 r;
        r.x = atomicAdd(&deg[d.x], 1);
        r.y = atomicAdd(&deg[d.y], 1);
        r.z = atomicAdd(&deg[d.z], 1);
        r.w = atomicAdd(&deg[d.w], 1);
        *(int4*)(rank + i) = r;
    } else {
        for (int k = i; k < E; ++k) rank[k] = atomicAdd(&deg[dst[k]], 1);
    }
}

// ---- exclusive scan of deg -> rowptr ----
__global__ __launch_bounds__(256) void scan1_kernel(const int* __restrict__ deg,
                                                    int* __restrict__ part,
                                                    int* __restrict__ bsum, int n) {
    __shared__ int ts[256];
    int b = blockIdx.x, t = threadIdx.x;
    int base = b * SCAN_B + t * 4;
    int v[4], sum = 0;
#pragma unroll
    for (int k = 0; k < 4; ++k) { int i = base + k; v[k] = (i < n) ? deg[i] : 0; sum += v[k]; }
    ts[t] = sum;
    __syncthreads();
    for (int off = 1; off < 256; off <<= 1) {
        int add = (t >= off) ? ts[t - off] : 0;
        __syncthreads();
        ts[t] += add;
        __syncthreads();
    }
    int run = ts[t] - sum;
#pragma unroll
    for (int k = 0; k < 4; ++k) { int i = base + k; if (i < n) part[i] = run; run += v[k]; }
    if (t == 255) bsum[b] = ts[255];
}

__global__ __launch_bounds__(256) void scan2_kernel(int* __restrict__ bsum, int nb) {
    __shared__ int ts[256];
    int t = threadIdx.x;
    int v = (t < nb) ? bsum[t] : 0;
    ts[t] = v;
    __syncthreads();
    for (int off = 1; off < 256; off <<= 1) {
        int add = (t >= off) ? ts[t - off] : 0;
        __syncthreads();
        ts[t] += add;
        __syncthreads();
    }
    if (t < nb) bsum[t] = ts[t] - v;
}

__global__ void scan3_kernel(const int* __restrict__ part, const int* __restrict__ bsum,
                             const int* __restrict__ deg, int* __restrict__ rowptr,
                             float* __restrict__ dinv, int n, int E) {
    int i = blockIdx.x * blockDim.x + threadIdx.x;
    if (i < n) {
        rowptr[i] = part[i] + bsum[i / SCAN_B];
        dinv[i] = rsqrtf((float)deg[i] + 1.0f);
    }
    if (i == 0) rowptr[n] = E;
}

// ---- atomic-free bucket fill (plain stores) ----
__global__ void fill_kernel(const int* __restrict__ src, const int* __restrict__ dst,
                            const int* __restrict__ rank, const int* __restrict__ rowptr,
                            int* __restrict__ csr_src, int E) {
    int i = (blockIdx.x * blockDim.x + threadIdx.x) * 4;
    if (i + 4 <= E) {
        int4 s = *(const int4*)(src + i);
        int4 d = *(const int4*)(dst + i);
        int4 r = *(const int4*)(rank + i);
        csr_src[rowptr[d.x] + r.x] = s.x;
        csr_src[rowptr[d.y] + r.y] = s.y;
        csr_src[rowptr[d.z] + r.z] = s.z;
        csr_src[rowptr[d.w] + r.w] = s.w;
    } else {
        for (int k = i; k < E; ++k) csr_src[rowptr[dst[k]] + rank[k]] = src[k];
    }
}

// ---- gemm1: y1[i][j] = fp16( scale[i] * (x[i] . W1[j]) ), fp32 input ----
__global__ __launch_bounds__(256) void gemm1_kernel(
    const float4* __restrict__ in4, const float* __restrict__ W,
    const float* __restrict__ scale, __half* __restrict__ yout, int n) {
    int tid = threadIdx.x;
    int lane = tid & 63;
    int m = lane & 15;
    float4 w[16];
#pragma unroll
    for (int t = 0; t < 16; ++t) w[t] = *(const float4*)(W + (size_t)lane * F + 4 * t);
    int gw = blockIdx.x * 4 + (tid >> 6);
    int nw = gridDim.x * 4;
    int node = gw;
    if (node >= n) return;
    float4 v = in4[(size_t)node * 16 + m];
    while (true) {
        int nxt = node + nw;
        float4 vn;
        if (nxt < n) vn = in4[(size_t)nxt * 16 + m];   // prefetch next row
        float acc = 0.0f;
#pragma unroll
        for (int t = 0; t < 16; ++t) {
            acc = fmaf(rl(v.x, t), w[t].x, acc);
            acc = fmaf(rl(v.y, t), w[t].y, acc);
            acc = fmaf(rl(v.z, t), w[t].z, acc);
            acc = fmaf(rl(v.w, t), w[t].w, acc);
        }
        acc *= scale[node];
        yout[(size_t)node * F + lane] = __float2half(acc);
        if (nxt >= n) break;
        v = vn;
        node = nxt;
    }
}

// ---- gemm2: y2[i][j] = fp16( (h1s[i] . W2[j]) ), fp16 input ----
__global__ __launch_bounds__(256) void gemm2_kernel(
    const unsigned long long* __restrict__ in8, const float* __restrict__ W,
    __half* __restrict__ yout, int n) {
    int tid = threadIdx.x;
    int lane = tid & 63;
    int m = lane & 15;
    float4 w[16];
#pragma unroll
    for (int t = 0; t < 16; ++t) w[t] = *(const float4*)(W + (size_t)lane * F + 4 * t);
    int gw = blockIdx.x * 4 + (tid >> 6);
    int nw = gridDim.x * 4;
    int node = gw;
    if (node >= n) return;
    float4 v = unpack_h4(in8[(size_t)node * 16 + m]);
    while (true) {
        int nxt = node + nw;
        float4 vn;
        if (nxt < n) vn = unpack_h4(in8[(size_t)nxt * 16 + m]);   // prefetch
        float acc = 0.0f;
#pragma unroll
        for (int t = 0; t < 16; ++t) {
            acc = fmaf(rl(v.x, t), w[t].x, acc);
            acc = fmaf(rl(v.y, t), w[t].y, acc);
            acc = fmaf(rl(v.z, t), w[t].z, acc);
            acc = fmaf(rl(v.w, t), w[t].w, acc);
        }
        yout[(size_t)node * F + lane] = __float2half(acc);
        if (nxt >= n) break;
        v = vn;
        node = nxt;
    }
}

// 8-deep gather body with one-stage index-prefetch pipeline.
// gacc0..3 accumulate (macro-private names); next group's indices are
// loaded while the current group's 8 row loads are in flight.
#define GATHER_CORE(YTAB)                                                     \
    float4 gacc0 = {0,0,0,0}, gacc1 = {0,0,0,0};                              \
    float4 gacc2 = {0,0,0,0}, gacc3 = {0,0,0,0};                              \
    int p = beg;                                                              \
    if (p + 8 <= end) {                                                       \
        int i0 = csr_src[p],     i1 = csr_src[p + 1];                         \
        int i2 = csr_src[p + 2], i3 = csr_src[p + 3];                         \
        int i4 = csr_src[p + 4], i5 = csr_src[p + 5];                         \
        int i6 = csr_src[p + 6], i7 = csr_src[p + 7];                         \
        while (true) {                                                        \
            unsigned long long r0 = YTAB[(size_t)i0 * 16 + m];                \
            unsigned long long r1 = YTAB[(size_t)i1 * 16 + m];                \
            unsigned long long r2 = YTAB[(size_t)i2 * 16 + m];                \
            unsigned long long r3 = YTAB[(size_t)i3 * 16 + m];                \
            unsigned long long r4 = YTAB[(size_t)i4 * 16 + m];                \
            unsigned long long r5 = YTAB[(size_t)i5 * 16 + m];                \
            unsigned long long r6 = YTAB[(size_t)i6 * 16 + m];                \
            unsigned long long r7 = YTAB[(size_t)i7 * 16 + m];                \
            int np = p + 8;                                                   \
            bool more = np + 8 <= end;                                        \
            if (more) {                                                       \
                i0 = csr_src[np];     i1 = csr_src[np + 1];                   \
                i2 = csr_src[np + 2]; i3 = csr_src[np + 3];                   \
                i4 = csr_src[np + 4]; i5 = csr_src[np + 5];                   \
                i6 = csr_src[np + 6]; i7 = csr_src[np + 7];                   \
            }                                                                 \
            float4 v0 = unpack_h4(r0), v1 = unpack_h4(r1);                    \
            float4 v2 = unpack_h4(r2), v3 = unpack_h4(r3);                    \
            float4 v4 = unpack_h4(r4), v5 = unpack_h4(r5);                    \
            float4 v6 = unpack_h4(r6), v7 = unpack_h4(r7);                    \
            gacc0.x += v0.x + v4.x; gacc0.y += v0.y + v4.y;                   \
            gacc0.z += v0.z + v4.z; gacc0.w += v0.w + v4.w;                   \
            gacc1.x += v1.x + v5.x; gacc1.y += v1.y + v5.y;                   \
            gacc1.z += v1.z + v5.z; gacc1.w += v1.w + v5.w;                   \
            gacc2.x += v2.x + v6.x; gacc2.y += v2.y + v6.y;                   \
            gacc2.z += v2.z + v6.z; gacc2.w += v2.w + v6.w;                   \
            gacc3.x += v3.x + v7.x; gacc3.y += v3.y + v7.y;                   \
            gacc3.z += v3.z + v7.z; gacc3.w += v3.w + v7.w;                   \
            p = np;                                                           \
            if (!more) break;                                                 \
        }                                                                     \
    }                                                                         \
    if (p + 4 <= end) {                                                       \
        int i0 = csr_src[p], i1 = csr_src[p + 1];                             \
        int i2 = csr_src[p + 2], i3 = csr_src[p + 3];                         \
        float4 v0 = unpack_h4(YTAB[(size_t)i0 * 16 + m]);                     \
        float4 v1 = unpack_h4(YTAB[(size_t)i1 * 16 + m]);                     \
        float4 v2 = unpack_h4(YTAB[(size_t)i2 * 16 + m]);                     \
        float4 v3 = unpack_h4(YTAB[(size_t)i3 * 16 + m]);                     \
        gacc0.x += v0.x; gacc0.y += v0.y; gacc0.z += v0.z; gacc0.w += v0.w;   \
        gacc1.x += v1.x; gacc1.y += v1.y; gacc1.z += v1.z; gacc1.w += v1.w;   \
        gacc2.x += v2.x; gacc2.y += v2.y; gacc2.z += v2.z; gacc2.w += v2.w;   \
        gacc3.x += v3.x; gacc3.y += v3.y; gacc3.z += v3.z; gacc3.w += v3.w;   \
        p += 4;                                                               \
    }                                                                         \
    for (; p < end; ++p) {                                                    \
        float4 v = unpack_h4(YTAB[(size_t)csr_src[p] * 16 + m]);              \
        gacc0.x += v.x; gacc0.y += v.y; gacc0.z += v.z; gacc0.w += v.w;       \
    }                                                                         \
    float4 a;                                                                 \
    a.x = gacc0.x + gacc1.x + gacc2.x + gacc3.x;                              \
    a.y = gacc0.y + gacc1.y + gacc2.y + gacc3.y;                              \
    a.z = gacc0.z + gacc1.z + gacc2.z + gacc3.z;                              \
    a.w = gacc0.w + gacc1.w + gacc2.w + gacc3.w;

// ---- gather1: quarter-wave per node -> h1s (fp16) ----
__global__ __launch_bounds__(256) void gather1_kernel(
    const unsigned long long* __restrict__ y, const int* __restrict__ rowptr,
    const int* __restrict__ csr_src, const float* __restrict__ dinv,
    const float* __restrict__ b1, __half* __restrict__ h1s, int n) {
    int tid = threadIdx.x;
    int m = tid & 15;
    float4 bias = *(const float4*)(b1 + 4 * m);
    int qid = (blockIdx.x * 256 + tid) >> 4;
    int nq = (gridDim.x * 256) >> 4;
    for (int node = qid; node < n; node += nq) {
        int beg = rowptr[node], end = rowptr[node + 1];
        GATHER_CORE(y)
        float dd = dinv[node];
        float4 self = unpack_h4(y[(size_t)node * 16 + m]);
        float4 r;
        r.x = dd * fmaxf(fmaf(dd, a.x + self.x, bias.x), 0.0f);
        r.y = dd * fmaxf(fmaf(dd, a.y + self.y, bias.y), 0.0f);
        r.z = dd * fmaxf(fmaf(dd, a.z + self.z, bias.z), 0.0f);
        r.w = dd * fmaxf(fmaf(dd, a.w + self.w, bias.w), 0.0f);
        __half2 lo = __float22half2_rn(make_float2(r.x, r.y));
        __half2 hi = __float22half2_rn(make_float2(r.z, r.w));
        float2 packed;
        packed.x = __builtin_bit_cast(float, lo);
        packed.y = __builtin_bit_cast(float, hi);
        *(float2*)(h1s + (size_t)node * F + 4 * m) = packed;
    }
}

// ---- gather2: quarter-wave per node + b2/relu + W3 (shfl) -> out ----
__global__ __launch_bounds__(256) void gather2_kernel(
    const unsigned long long* __restrict__ y, const int* __restrict__ rowptr,
    const int* __restrict__ csr_src, const float* __restrict__ dinv,
    const float* __restrict__ b2, const float* __restrict__ W3,
    const float* __restrict__ b3, float* __restrict__ out, int n) {
    int tid = threadIdx.x;
    int lane = tid & 63;
    int m = lane & 15;
    int qbase = lane & 48;
    float4 bias = *(const float4*)(b2 + 4 * m);
    float b3r = b3[m];
    int qid = (blockIdx.x * 256 + tid) >> 4;
    int nq = (gridDim.x * 256) >> 4;
    for (int node = qid; node < n; node += nq) {
        int beg = rowptr[node], end = rowptr[node + 1];
        GATHER_CORE(y)
        float dd = dinv[node];
        float4 self = unpack_h4(y[(size_t)node * 16 + m]);
        float4 h;   // lane m of quarter: h2 features [4m..4m+3]
        h.x = fmaxf(fmaf(dd, a.x + self.x, bias.x), 0.0f);
        h.y = fmaxf(fmaf(dd, a.y + self.y, bias.y), 0.0f);
        h.z = fmaxf(fmaf(dd, a.z + self.z, bias.z), 0.0f);
        h.w = fmaxf(fmaf(dd, a.w + self.w, bias.w), 0.0f);
        float acc3 = 0.0f;
#pragma unroll
        for (int t = 0; t < 16; ++t) {
            float4 wv = *(const float4*)(W3 + (size_t)m * F + 4 * t);   // L1-hot
            float hx = __shfl(h.x, qbase + t);
            float hy = __shfl(h.y, qbase + t);
            float hz = __shfl(h.z, qbase + t);
            float hw = __shfl(h.w, qbase + t);
            acc3 = fmaf(hx, wv.x, fmaf(hy, wv.y, fmaf(hz, wv.z, fmaf(hw, wv.w, acc3))));
        }
        out[(size_t)node * C + m] = acc3 + b3r;
    }
}

extern "C" void kernel_launch(void* const* d_in, const int* in_sizes, int n_in,
                              void* d_out, int out_size, void* d_ws, size_t ws_size,
                              hipStream_t stream) {
    const float* x  = (const float*)d_in[0];
    const int* edge = (const int*)d_in[1];
    const float* W1 = (const float*)d_in[2];
    const float* b1 = (const float*)d_in[3];
    const float* W2 = (const float*)d_in[4];
    const float* b2 = (const float*)d_in[5];
    const float* W3 = (const float*)d_in[6];
    const float* b3 = (const float*)d_in[7];
    float* out = (float*)d_out;

    int n = in_sizes[0] / F;        // 100000
    int E = in_sizes[1] / 2;        // 1600000
    const int* src = edge;
    const int* dst = edge + E;

    int nb = (n + SCAN_B - 1) / SCAN_B;

    char* ws = (char*)d_ws;
    size_t o = 0;
    auto alloc = [&](size_t bytes) { char* p = ws + o; o += (bytes + 255) & ~(size_t)255; return p; };
    int*    deg     = (int*)   alloc((size_t)n * 4);
    int*    rank    = (int*)   alloc((size_t)E * 4);
    int*    part    = (int*)   alloc((size_t)n * 4);
    int*    bsum    = (int*)   alloc(256 * 4);
    int*    rowptr  = (int*)   alloc((size_t)(n + 1) * 4);
    int*    csr_src = (int*)   alloc((size_t)E * 4);
    float*  dinv    = (float*) alloc((size_t)n * 4);
    __half* y1      = (__half*)alloc((size_t)n * F * 2);   // reused as y2
    __half* h1s     = (__half*)alloc((size_t)n * F * 2);
    __half* y2      = y1;                                   // y1 dead after gather1

    hipMemsetAsync(deg, 0, (size_t)n * 4, stream);
    degrank_kernel<<<(E / 4 + 255) / 256, 256, 0, stream>>>(dst, deg, rank, E);

    scan1_kernel<<<nb, 256, 0, stream>>>(deg, part, bsum, n);
    scan2_kernel<<<1, 256, 0, stream>>>(bsum, nb);
    scan3_kernel<<<(n + 255) / 256, 256, 0, stream>>>(part, bsum, deg, rowptr, dinv, n, E);

    // y1 = fp16( dinv .* (x @ W1^T) )
    gemm1_kernel<<<2048, 256, 0, stream>>>((const float4*)x, W1, dinv, y1, n);

    fill_kernel<<<(E / 4 + 255) / 256, 256, 0, stream>>>(src, dst, rank, rowptr, csr_src, E);

    gather1_kernel<<<2048, 256, 0, stream>>>(
        (const unsigned long long*)y1, rowptr, csr_src, dinv, b1, h1s, n);

    // y2 = fp16( h1s @ W2^T )
    gemm2_kernel<<<2048, 256, 0, stream>>>(
        (const unsigned long long*)h1s, W2, y2, n);

    gather2_kernel<<<2048, 256, 0, stream>>>(
        (const unsigned long long*)y2, rowptr, csr_src, dinv, b2, W3, b3, out, n);
}